// Round 13
// baseline (134.678 us; speedup 1.0000x reference)
//
#include <hip/hip_runtime.h>

// MMD loss, N=4096 per side, D=256, fp32.
// R13: single-pass bf16 MFMA Gram (HW-verified absmax 0.0 since R10).
//      vs R12 (116 us, k_pairs 51):
//      1) SUPERTILE-MAJOR tile order: consecutive ~64 blocks share one 8x8-
//         panel supertile (16 panels = 1 MB); all XCDs march through 1-2
//         supertiles together -> L2-resident fragments (R12's band decode
//         touched all 64 panels per XCD = 4 MB = exactly L2 -> thrash to LLC,
//         ~600cyc loads, MfmaUtil 12%).
//      2) 4 dispatches -> 2 kernels + 2 tiny memsets: scale computed per-block
//         in k_pairs epilogue (S1 + colsum via k_conv atomics, stream-ordered
//         visibility, NO fences — R8-R10 lesson); output atomicAdd'ed
//         pre-normalized into d_out (float jitter ~1e-6 << 2.9e-5 threshold).
//      k_pairs: barrier-free K-loop, BK=64 batch, frag arrays indexed only by
//      immediately-unrolled vars (R8/R9 SROA lesson). Tiled bf16 plane (R6).

#define NROWS 8192
#define HALF  4096
#define DIM   256
#define BM    128
#define CONVB 256         // k_conv blocks; 32 rows each (quarter panel)
#define NTILE 2080        // upper-tri tile count for 128-tiles

typedef __bf16 bf16x8 __attribute__((ext_vector_type(8)));
typedef float f32x4 __attribute__((ext_vector_type(4)));
typedef unsigned short ushort8 __attribute__((ext_vector_type(8)));

__device__ __forceinline__ const float* row_ptr(const float* src, const float* tgt, int r) {
    return (r < HALF) ? (src + (size_t)r * DIM) : (tgt + (size_t)(r - HALF) * DIM);
}

__device__ __forceinline__ unsigned short bf16_rne(float x) {
    unsigned int u = __builtin_bit_cast(unsigned int, x);
    return (unsigned short)((u + 0x7FFFu + ((u >> 16) & 1u)) >> 16);
}

// --- Phase 0: fp32 -> bf16 plane (tiled) + sq[] + colsum/S1 (atomics) ---
// Tiled plane layout: 16B-granule index of (global row R, k-granule g) =
//   (R>>7)*4096 + g*128 + (R&127)        [panel-major, granule-major inside]
__global__ __launch_bounds__(256) void k_conv(const float* __restrict__ src,
                                              const float* __restrict__ tgt,
                                              unsigned short* __restrict__ hi,
                                              float* __restrict__ sq,
                                              float* __restrict__ colsum,
                                              double* __restrict__ s1acc) {
    __shared__ __align__(16) unsigned short sh_hi[32 * 32 * 8];  // 16 KB
    __shared__ float4 cs[4][64];
    __shared__ double s1s[4];

    int w = threadIdx.x >> 6, lane = threadIdx.x & 63;
    int r0 = blockIdx.x * 32;                       // 32 rows per block
    int g  = lane >> 1, j = lane & 1;               // lane's float4 = half-granule
    float4 csum = {0.f, 0.f, 0.f, 0.f};
    double s1w = 0.0;
    #pragma unroll
    for (int i = 0; i < 8; ++i) {
        int rl  = w * 8 + i;                        // local row 0..31
        int row = r0 + rl;
        const float* rp = row_ptr(src, tgt, row);
        float4 v = ((const float4*)rp)[lane];       // coalesced: 64 lanes * 16 B
        float xs[4] = {v.x, v.y, v.z, v.w};
        unsigned short hs[4];
        #pragma unroll
        for (int k = 0; k < 4; ++k) hs[k] = bf16_rne(xs[k]);
        ushort4 h4 = {hs[0], hs[1], hs[2], hs[3]};
        int so = (g * 32 + rl) * 8 + j * 4;
        *(ushort4*)&sh_hi[so] = h4;
        csum.x += v.x; csum.y += v.y; csum.z += v.z; csum.w += v.w;
        float s = v.x * v.x + v.y * v.y + v.z * v.z + v.w * v.w;
        #pragma unroll
        for (int off = 32; off; off >>= 1) s += __shfl_xor(s, off, 64);
        if (lane == 0) { sq[row] = s; s1w += (double)s; }
    }
    __syncthreads();
    // Coalesced tiled write-out: 1024 chunks of 16 B.
    int panel = blockIdx.x >> 2, quarter = blockIdx.x & 3;
    #pragma unroll
    for (int c = threadIdx.x; c < 1024; c += 256) {
        int gg = c >> 5, r = c & 31;
        size_t goff = (((size_t)panel * 32 + gg) * 128 + quarter * 32 + r) * 8;
        *(ushort8*)&hi[goff] = *(const ushort8*)&sh_hi[c * 8];
    }
    // colsum + S1 accumulation (plain device atomics, no fences)
    cs[w][lane] = csum;
    if (lane == 0) s1s[w] = s1w;
    __syncthreads();
    if (w == 0) {
        float4 a = cs[0][lane], b = cs[1][lane], c = cs[2][lane], d = cs[3][lane];
        atomicAdd(&colsum[lane * 4 + 0], a.x + b.x + c.x + d.x);
        atomicAdd(&colsum[lane * 4 + 1], a.y + b.y + c.y + d.y);
        atomicAdd(&colsum[lane * 4 + 2], a.z + b.z + c.z + d.z);
        atomicAdd(&colsum[lane * 4 + 3], a.w + b.w + c.w + d.w);
        if (lane == 0) atomicAdd(s1acc, s1s[0] + s1s[1] + s1s[2] + s1s[3]);
    }
}

// --- Phase 1: barrier-free single-pass bf16 MFMA pair kernel ---
__global__ __launch_bounds__(256, 4) void k_pairs(const unsigned short* __restrict__ hi,
                                                  const float* __restrict__ sq,
                                                  const float* __restrict__ colsum,
                                                  const double* __restrict__ s1acc,
                                                  float* __restrict__ out) {
    // Supertile-major decode: row-group I holds supertiles (I,I..7); within a
    // supertile (16 panels, 1 MB) tiles are contiguous in blockIdx -> the chip
    // works 1-2 supertiles at a time -> L2-resident.
    int gidx = blockIdx.x;
    int I = 0;
    for (;;) {
        int rowcnt = 36 + 64 * (7 - I);
        if (gidx < rowcnt) break;
        gidx -= rowcnt; ++I;
    }
    int bi, bj;
    if (gidx < 36) {                                // diagonal supertile (I,I)
        int r = 0, c = gidx;
        while (c >= 8 - r) { c -= 8 - r; ++r; }
        bi = 8 * I + r; bj = 8 * I + r + c;
    } else {                                        // off-diagonal (I,J)
        int o = gidx - 36;
        int J = I + 1 + (o >> 6);
        int k2 = o & 63;
        bi = 8 * I + (k2 >> 3); bj = 8 * J + (k2 & 7);
    }

    __shared__ float wsum[4];
    __shared__ double sred[4];
    __shared__ float sc_sh;

    int t    = threadIdx.x;
    int lane = t & 63;
    int w    = t >> 6;
    int wr   = w >> 1, wc = w & 1;                  // 2x2 wave grid, 64x64 each
    int lr   = lane & 15, lq = lane >> 4;
    int ro = bi * BM, co = bj * BM;

    size_t aBase = (size_t)bi * 4096 + lq * 128 + wr * 64 + lr;
    size_t bBase = (size_t)bj * 4096 + lq * 128 + wc * 64 + lr;
    const ushort8* pAh = (const ushort8*)hi + aBase;
    const ushort8* pBh = (const ushort8*)hi + bBase;

    f32x4 acc[4][4];
    #pragma unroll
    for (int m = 0; m < 4; ++m)
        #pragma unroll
        for (int n = 0; n < 4; ++n) acc[m][n] = (f32x4){0.f, 0.f, 0.f, 0.f};

    #pragma unroll
    for (int it = 0; it < DIM / 64; ++it) {
        // 16 coalesced loads (two k32-chunks), then 32 MFMAs. Arrays indexed
        // only by immediately-unrolled h/m/n -> pure registers (no scratch).
        bf16x8 aH[2][4], bH[2][4];
        #pragma unroll
        for (int h = 0; h < 2; ++h) {
            #pragma unroll
            for (int m = 0; m < 4; ++m) {
                aH[h][m] = __builtin_bit_cast(bf16x8, pAh[it * 1024 + h * 512 + m * 16]);
                bH[h][m] = __builtin_bit_cast(bf16x8, pBh[it * 1024 + h * 512 + m * 16]);
            }
        }
        #pragma unroll
        for (int h = 0; h < 2; ++h)
            #pragma unroll
            for (int m = 0; m < 4; ++m)
                #pragma unroll
                for (int n = 0; n < 4; ++n)
                    acc[m][n] = __builtin_amdgcn_mfma_f32_16x16x32_bf16(aH[h][m], bH[h][n], acc[m][n], 0, 0, 0);
    }

    // ---- per-block bandwidth scale (identical in every block; ~500 cyc)
    double c2 = (double)colsum[t] * (double)colsum[t];
    #pragma unroll
    for (int off = 32; off; off >>= 1) c2 += __shfl_xor(c2, off, 64);
    if (lane == 0) sred[w] = c2;
    __syncthreads();
    if (t == 0) {
        double S2 = sred[0] + sred[1] + sred[2] + sred[3];
        double S1 = *s1acc;
        double n  = (double)NROWS;
        double sumL2 = 2.0 * n * S1 - 2.0 * S2;
        double bw = sumL2 / (n * n - n) / 4.0;      // / KERNEL_MUL^(KERNEL_NUM//2)
        sc_sh = (float)(-1.0 / (16.0 * bw * 0.69314718055994530942));
    }
    __syncthreads();
    float scale = sc_sh;

    // ---- epilogue: L2 -> sum of 5 Gaussian kernels -> reduce
    int ro_eff = ro + wr * 64, co_eff = co + wc * 64;
    float4 sqa4[4];
    float  sqbv[4];
    #pragma unroll
    for (int m = 0; m < 4; ++m) sqa4[m] = *(const float4*)&sq[ro_eff + m * 16 + lq * 4];
    #pragma unroll
    for (int n = 0; n < 4; ++n) sqbv[n] = sq[co_eff + n * 16 + lr];

    float tsum = 0.0f;
    #pragma unroll
    for (int m = 0; m < 4; ++m) {
        float sa[4] = {sqa4[m].x, sqa4[m].y, sqa4[m].z, sqa4[m].w};
        #pragma unroll
        for (int n = 0; n < 4; ++n) {
            #pragma unroll
            for (int r = 0; r < 4; ++r) {
                float L2  = sa[r] + sqbv[n] - 2.0f * acc[m][n][r];
                float u   = __builtin_amdgcn_exp2f(scale * L2);
                float u2  = u * u;
                float u4  = u2 * u2;
                float u8  = u4 * u4;
                float u16 = u8 * u8;
                tsum += u + u2 + u4 + u8 + u16;     // 5 kernel scales
            }
        }
    }

    #pragma unroll
    for (int off = 32; off; off >>= 1) tsum += __shfl_xor(tsum, off, 64);
    if (lane == 0) wsum[w] = tsum;
    __syncthreads();
    if (t == 0) {
        float tot = wsum[0] + wsum[1] + wsum[2] + wsum[3];
        float sgn = ((ro < HALF) == (co < HALF)) ? 1.0f : -1.0f;
        float wgt = (bi == bj) ? 1.0f : 2.0f;       // off-diag tiles stand for (i,j)+(j,i)
        // pre-normalized float atomic straight into d_out (jitter ~1e-6)
        atomicAdd(out, sgn * wgt * tot * (1.0f / ((float)HALF * (float)HALF)));
    }
}

extern "C" void kernel_launch(void* const* d_in, const int* in_sizes, int n_in,
                              void* d_out, int out_size, void* d_ws, size_t ws_size,
                              hipStream_t stream) {
    const float* src = (const float*)d_in[0];
    const float* tgt = (const float*)d_in[1];
    float* out = (float*)d_out;

    char* ws = (char*)d_ws;
    double* s1acc  = (double*)ws;                                // 8 B
    float*  colsum = (float*)(ws + 64);                          // 1024 B
    float*  sq     = (float*)(ws + 2048);                        // 32768 B
    unsigned short* hi = (unsigned short*)(ws + 65536);          // 4 MB, 16B-aligned

    hipMemsetAsync(ws, 0, 1088, stream);            // s1acc + colsum
    hipMemsetAsync(d_out, 0, sizeof(float), stream);
    k_conv <<<CONVB, 256, 0, stream>>>(src, tgt, hi, sq, colsum, s1acc);
    k_pairs<<<NTILE, 256, 0, stream>>>(hi, sq, colsum, s1acc, out);
}

// Round 14
// 112.690 us; speedup vs baseline: 1.1951x; 1.1951x over previous
//
#include <hip/hip_runtime.h>

// MMD loss, N=4096 per side, D=256, fp32.
// R14: single-pass bf16 MFMA Gram (HW-verified absmax 0.0 since R10).
//      Skeleton reverted to R12's proven 4-launch form (R13's fusion was a
//      false economy: memsets are dispatches too, colsum atomics contended,
//      per-block scale redundant -> total 116->135 regression).
//      k_pairs vs R12/R13: BK=128 — all 32 fragment loads (both k-halves,
//      128 VGPR) issue before a 64-MFMA burst -> 2 latency exposures per wave
//      instead of 4. Rationale: FETCH 18MB / 66MB logical = ~27% L2 miss,
//      ~600-900cyc LLC latency per exposure is the stall (MfmaUtil 14%).
//      Supertile-major decode kept (R13's one positive delta).
//      Frag arrays indexed only by immediately-unrolled vars (SROA lesson).
//      NO __threadfence anywhere (R8-R10 L2-flush lesson).

#define NROWS 8192
#define HALF  4096
#define DIM   256
#define BM    128
#define CONVB 256         // k_conv blocks; 32 rows each (quarter panel)
#define NTILE 2080        // upper-tri tile count for 128-tiles

typedef __bf16 bf16x8 __attribute__((ext_vector_type(8)));
typedef float f32x4 __attribute__((ext_vector_type(4)));
typedef unsigned short ushort8 __attribute__((ext_vector_type(8)));

__device__ __forceinline__ const float* row_ptr(const float* src, const float* tgt, int r) {
    return (r < HALF) ? (src + (size_t)r * DIM) : (tgt + (size_t)(r - HALF) * DIM);
}

__device__ __forceinline__ unsigned short bf16_rne(float x) {
    unsigned int u = __builtin_bit_cast(unsigned int, x);
    return (unsigned short)((u + 0x7FFFu + ((u >> 16) & 1u)) >> 16);
}

// --- Phase 0: fp32 -> bf16 plane (tiled) + sq[] + colsum/S1 partials ---
// Tiled plane layout: 16B-granule index of (global row R, k-granule g) =
//   (R>>7)*4096 + g*128 + (R&127)        [panel-major, granule-major inside]
__global__ __launch_bounds__(256) void k_conv(const float* __restrict__ src,
                                              const float* __restrict__ tgt,
                                              unsigned short* __restrict__ hi,
                                              float* __restrict__ sq,
                                              float* __restrict__ part,
                                              double* __restrict__ parts1,
                                              double* __restrict__ accum) {
    __shared__ __align__(16) unsigned short sh_hi[32 * 32 * 8];  // 16 KB
    __shared__ float4 cs[4][64];
    __shared__ double s1s[4];

    int w = threadIdx.x >> 6, lane = threadIdx.x & 63;
    int r0 = blockIdx.x * 32;                       // 32 rows per block
    int g  = lane >> 1, j = lane & 1;               // lane's float4 = half-granule
    float4 csum = {0.f, 0.f, 0.f, 0.f};
    double s1w = 0.0;
    #pragma unroll
    for (int i = 0; i < 8; ++i) {
        int rl  = w * 8 + i;                        // local row 0..31
        int row = r0 + rl;
        const float* rp = row_ptr(src, tgt, row);
        float4 v = ((const float4*)rp)[lane];       // coalesced: 64 lanes * 16 B
        float xs[4] = {v.x, v.y, v.z, v.w};
        unsigned short hs[4];
        #pragma unroll
        for (int k = 0; k < 4; ++k) hs[k] = bf16_rne(xs[k]);
        ushort4 h4 = {hs[0], hs[1], hs[2], hs[3]};
        int so = (g * 32 + rl) * 8 + j * 4;
        *(ushort4*)&sh_hi[so] = h4;
        csum.x += v.x; csum.y += v.y; csum.z += v.z; csum.w += v.w;
        float s = v.x * v.x + v.y * v.y + v.z * v.z + v.w * v.w;
        #pragma unroll
        for (int off = 32; off; off >>= 1) s += __shfl_xor(s, off, 64);
        if (lane == 0) { sq[row] = s; s1w += (double)s; }
    }
    __syncthreads();
    // Coalesced tiled write-out: 1024 chunks of 16 B.
    int panel = blockIdx.x >> 2, quarter = blockIdx.x & 3;
    #pragma unroll
    for (int c = threadIdx.x; c < 1024; c += 256) {
        int gg = c >> 5, r = c & 31;
        size_t goff = (((size_t)panel * 32 + gg) * 128 + quarter * 32 + r) * 8;
        *(ushort8*)&hi[goff] = *(const ushort8*)&sh_hi[c * 8];
    }
    // colsum + S1 partials (per-block slots, no contention)
    cs[w][lane] = csum;
    if (lane == 0) s1s[w] = s1w;
    __syncthreads();
    if (w == 0) {
        float4 a = cs[0][lane], b = cs[1][lane], c = cs[2][lane], d = cs[3][lane];
        float4 tot = {a.x + b.x + c.x + d.x, a.y + b.y + c.y + d.y,
                      a.z + b.z + c.z + d.z, a.w + b.w + c.w + d.w};
        *(float4*)&part[(size_t)blockIdx.x * DIM + lane * 4] = tot;
        if (lane == 0) parts1[blockIdx.x] = s1s[0] + s1s[1] + s1s[2] + s1s[3];
    }
    if (blockIdx.x == 0 && threadIdx.x == 0) *accum = 0.0;
}

// --- Phase 1: bandwidth -> exp2 scale factor (pipelined reductions) ---
__global__ __launch_bounds__(256) void k_scale(const double* __restrict__ parts1,
                                               const float* __restrict__ part,
                                               float* __restrict__ scale) {
    __shared__ double sh[256];
    int t = threadIdx.x;
    sh[t] = parts1[t];
    __syncthreads();
    for (int off = 128; off; off >>= 1) {
        if (t < off) sh[t] += sh[t + off];
        __syncthreads();
    }
    double S1 = sh[0];
    __syncthreads();
    float c0 = 0.f, c1 = 0.f, c2 = 0.f, c3 = 0.f;
    #pragma unroll 16
    for (int b = 0; b < CONVB; b += 4) {
        c0 += part[(b + 0) * DIM + t];
        c1 += part[(b + 1) * DIM + t];
        c2 += part[(b + 2) * DIM + t];
        c3 += part[(b + 3) * DIM + t];
    }
    double c = (double)((c0 + c1) + (c2 + c3));
    sh[t] = c * c;
    __syncthreads();
    for (int off = 128; off; off >>= 1) {
        if (t < off) sh[t] += sh[t + off];
        __syncthreads();
    }
    if (t == 0) {
        double S2    = sh[0];
        double n     = (double)NROWS;
        double sumL2 = 2.0 * n * S1 - 2.0 * S2;
        double bw    = sumL2 / (n * n - n) / 4.0;   // / KERNEL_MUL^(KERNEL_NUM//2)
        // u = exp(-L2/(16*bw)) = exp2(scale * L2)
        *scale = (float)(-1.0 / (16.0 * bw * 0.69314718055994530942));
    }
}

// --- Phase 2: barrier-free single-pass bf16 MFMA pair kernel, BK=128 ---
__global__ __launch_bounds__(256, 2) void k_pairs(const unsigned short* __restrict__ hi,
                                                  const float* __restrict__ sq,
                                                  const float* __restrict__ scale_p,
                                                  double* __restrict__ accum) {
    // Supertile-major decode: row-group I holds supertiles (I,I..7); within a
    // supertile (16 panels, 1 MB) tiles are contiguous in blockIdx.
    int gidx = blockIdx.x;
    int I = 0;
    for (;;) {
        int rowcnt = 36 + 64 * (7 - I);
        if (gidx < rowcnt) break;
        gidx -= rowcnt; ++I;
    }
    int bi, bj;
    if (gidx < 36) {                                // diagonal supertile (I,I)
        int r = 0, c = gidx;
        while (c >= 8 - r) { c -= 8 - r; ++r; }
        bi = 8 * I + r; bj = 8 * I + r + c;
    } else {                                        // off-diagonal (I,J)
        int o = gidx - 36;
        int J = I + 1 + (o >> 6);
        int k2 = o & 63;
        bi = 8 * I + (k2 >> 3); bj = 8 * J + (k2 & 7);
    }

    __shared__ float wsum[4];

    int t    = threadIdx.x;
    int lane = t & 63;
    int w    = t >> 6;
    int wr   = w >> 1, wc = w & 1;                  // 2x2 wave grid, 64x64 each
    int lr   = lane & 15, lq = lane >> 4;
    int ro = bi * BM, co = bj * BM;

    size_t aBase = (size_t)bi * 4096 + lq * 128 + wr * 64 + lr;
    size_t bBase = (size_t)bj * 4096 + lq * 128 + wc * 64 + lr;
    const ushort8* pAh = (const ushort8*)hi + aBase;
    const ushort8* pBh = (const ushort8*)hi + bBase;

    f32x4 acc[4][4];
    #pragma unroll
    for (int m = 0; m < 4; ++m)
        #pragma unroll
        for (int n = 0; n < 4; ++n) acc[m][n] = (f32x4){0.f, 0.f, 0.f, 0.f};

    #pragma unroll
    for (int it = 0; it < DIM / 128; ++it) {
        // 32 coalesced loads (four k32-chunks = 128 VGPR of fragments) issue
        // before a 64-MFMA burst: 2 latency exposures per wave total.
        // Arrays indexed only by immediately-unrolled h/m/n -> pure registers.
        bf16x8 aH[4][4], bH[4][4];
        #pragma unroll
        for (int h = 0; h < 4; ++h) {
            #pragma unroll
            for (int m = 0; m < 4; ++m) {
                aH[h][m] = __builtin_bit_cast(bf16x8, pAh[it * 2048 + h * 512 + m * 16]);
                bH[h][m] = __builtin_bit_cast(bf16x8, pBh[it * 2048 + h * 512 + m * 16]);
            }
        }
        #pragma unroll
        for (int h = 0; h < 4; ++h)
            #pragma unroll
            for (int m = 0; m < 4; ++m)
                #pragma unroll
                for (int n = 0; n < 4; ++n)
                    acc[m][n] = __builtin_amdgcn_mfma_f32_16x16x32_bf16(aH[h][m], bH[h][n], acc[m][n], 0, 0, 0);
    }

    // ---- epilogue: L2 -> sum of 5 Gaussian kernels -> reduce
    float scale = *scale_p;
    int ro_eff = ro + wr * 64, co_eff = co + wc * 64;
    float4 sqa4[4];
    float  sqbv[4];
    #pragma unroll
    for (int m = 0; m < 4; ++m) sqa4[m] = *(const float4*)&sq[ro_eff + m * 16 + lq * 4];
    #pragma unroll
    for (int n = 0; n < 4; ++n) sqbv[n] = sq[co_eff + n * 16 + lr];

    float tsum = 0.0f;
    #pragma unroll
    for (int m = 0; m < 4; ++m) {
        float sa[4] = {sqa4[m].x, sqa4[m].y, sqa4[m].z, sqa4[m].w};
        #pragma unroll
        for (int n = 0; n < 4; ++n) {
            #pragma unroll
            for (int r = 0; r < 4; ++r) {
                float L2  = sa[r] + sqbv[n] - 2.0f * acc[m][n][r];
                float u   = __builtin_amdgcn_exp2f(scale * L2);
                float u2  = u * u;
                float u4  = u2 * u2;
                float u8  = u4 * u4;
                float u16 = u8 * u8;
                tsum += u + u2 + u4 + u8 + u16;     // 5 kernel scales
            }
        }
    }

    #pragma unroll
    for (int off = 32; off; off >>= 1) tsum += __shfl_xor(tsum, off, 64);
    if (lane == 0) wsum[w] = tsum;
    __syncthreads();
    if (t == 0) {
        float tot = wsum[0] + wsum[1] + wsum[2] + wsum[3];
        float sgn = ((ro < HALF) == (co < HALF)) ? 1.0f : -1.0f;
        float wgt = (bi == bj) ? 1.0f : 2.0f;       // off-diag tiles stand for (i,j)+(j,i)
        atomicAdd(accum, (double)(sgn * wgt * tot));
    }
}

// --- Finalize: mean normalization ---
__global__ void k_fin(const double* __restrict__ accum, float* __restrict__ out) {
    out[0] = (float)(*accum / ((double)HALF * (double)HALF));
}

extern "C" void kernel_launch(void* const* d_in, const int* in_sizes, int n_in,
                              void* d_out, int out_size, void* d_ws, size_t ws_size,
                              hipStream_t stream) {
    const float* src = (const float*)d_in[0];
    const float* tgt = (const float*)d_in[1];
    float* out = (float*)d_out;

    char* ws = (char*)d_ws;
    double* accum  = (double*)ws;                                // 8 B
    float*  scale  = (float*)(ws + 16);                          // 4 B
    float*  sq     = (float*)(ws + 64);                          // 32768 B
    float*  part   = (float*)(ws + 64 + 32768);                  // 256*256*4 B
    double* parts1 = (double*)(ws + 64 + 32768 + 262144);        // 256*8 B
    unsigned short* hi = (unsigned short*)(ws + 297024);         // 4 MB, 16B-aligned

    k_conv <<<CONVB, 256, 0, stream>>>(src, tgt, hi, sq, part, parts1, accum);
    k_scale<<<1, 256, 0, stream>>>(parts1, part, scale);
    k_pairs<<<NTILE, 256, 0, stream>>>(hi, sq, scale, accum);
    k_fin  <<<1, 1, 0, stream>>>(accum, out);
}

// Round 15
// 110.892 us; speedup vs baseline: 1.2145x; 1.0162x over previous
//
#include <hip/hip_runtime.h>

// MMD loss, N=4096 per side, D=256, fp32.
// R15: single-pass bf16 MFMA Gram (HW-verified absmax 0.0 since R10).
//      k_pairs restructured to 256x128 tiles: each wave 64x128 -> per k-chunk
//      12 fragment loads + 32 MFMAs (~620 SIMD-cyc). Rationale: R7/R11/R14
//      (BK=32/64/128) all ~46us, VGPR=60 -> compiler always sinks loads to
//      uses; the 2 resident waves/SIMD ping-pong, so per-exposure MFMA burst
//      must exceed ~600-900cyc load latency. Old 16-MFMA burst (310cyc) left
//      a ~50% hole (MfmaUtil 14%). 32-MFMA burst covers it.
//      Also: blocks 2080->1056, fragment traffic 532->203 MB, I-major order
//      keeps A panel-pair L2-hot. Per-wave upper-tri weights: wave panel
//      Pw=2I+(w>>1); wgt = J==Pw?1 : J>Pw?2 : 0 (exact single cover).
//      Skeleton (k_conv/k_scale/k_fin) = R12/R14 proven form.
//      NO __threadfence (R8-R10 L2-flush lesson); frag/acc arrays indexed
//      only by immediately-unrolled vars (R8/R9 SROA lesson).

#define NROWS 8192
#define HALF  4096
#define DIM   256
#define CONVB 256         // k_conv blocks; 32 rows each (quarter panel)
#define NTILE 1056        // 256x128 tiles: sum_{I=0..31}(64-2I)

typedef __bf16 bf16x8 __attribute__((ext_vector_type(8)));
typedef float f32x4 __attribute__((ext_vector_type(4)));
typedef unsigned short ushort8 __attribute__((ext_vector_type(8)));

__device__ __forceinline__ const float* row_ptr(const float* src, const float* tgt, int r) {
    return (r < HALF) ? (src + (size_t)r * DIM) : (tgt + (size_t)(r - HALF) * DIM);
}

__device__ __forceinline__ unsigned short bf16_rne(float x) {
    unsigned int u = __builtin_bit_cast(unsigned int, x);
    return (unsigned short)((u + 0x7FFFu + ((u >> 16) & 1u)) >> 16);
}

// --- Phase 0: fp32 -> bf16 plane (tiled) + sq[] + colsum/S1 partials ---
// Tiled plane layout: 16B-granule index of (global row R, k-granule g) =
//   (R>>7)*4096 + g*128 + (R&127)        [panel-major, granule-major inside]
__global__ __launch_bounds__(256) void k_conv(const float* __restrict__ src,
                                              const float* __restrict__ tgt,
                                              unsigned short* __restrict__ hi,
                                              float* __restrict__ sq,
                                              float* __restrict__ part,
                                              double* __restrict__ parts1,
                                              double* __restrict__ accum) {
    __shared__ __align__(16) unsigned short sh_hi[32 * 32 * 8];  // 16 KB
    __shared__ float4 cs[4][64];
    __shared__ double s1s[4];

    int w = threadIdx.x >> 6, lane = threadIdx.x & 63;
    int r0 = blockIdx.x * 32;                       // 32 rows per block
    int g  = lane >> 1, j = lane & 1;               // lane's float4 = half-granule
    float4 csum = {0.f, 0.f, 0.f, 0.f};
    double s1w = 0.0;
    #pragma unroll
    for (int i = 0; i < 8; ++i) {
        int rl  = w * 8 + i;                        // local row 0..31
        int row = r0 + rl;
        const float* rp = row_ptr(src, tgt, row);
        float4 v = ((const float4*)rp)[lane];       // coalesced: 64 lanes * 16 B
        float xs[4] = {v.x, v.y, v.z, v.w};
        unsigned short hs[4];
        #pragma unroll
        for (int k = 0; k < 4; ++k) hs[k] = bf16_rne(xs[k]);
        ushort4 h4 = {hs[0], hs[1], hs[2], hs[3]};
        int so = (g * 32 + rl) * 8 + j * 4;
        *(ushort4*)&sh_hi[so] = h4;
        csum.x += v.x; csum.y += v.y; csum.z += v.z; csum.w += v.w;
        float s = v.x * v.x + v.y * v.y + v.z * v.z + v.w * v.w;
        #pragma unroll
        for (int off = 32; off; off >>= 1) s += __shfl_xor(s, off, 64);
        if (lane == 0) { sq[row] = s; s1w += (double)s; }
    }
    __syncthreads();
    // Coalesced tiled write-out: 1024 chunks of 16 B.
    int panel = blockIdx.x >> 2, quarter = blockIdx.x & 3;
    #pragma unroll
    for (int c = threadIdx.x; c < 1024; c += 256) {
        int gg = c >> 5, r = c & 31;
        size_t goff = (((size_t)panel * 32 + gg) * 128 + quarter * 32 + r) * 8;
        *(ushort8*)&hi[goff] = *(const ushort8*)&sh_hi[c * 8];
    }
    // colsum + S1 partials (per-block slots, no contention)
    cs[w][lane] = csum;
    if (lane == 0) s1s[w] = s1w;
    __syncthreads();
    if (w == 0) {
        float4 a = cs[0][lane], b = cs[1][lane], c = cs[2][lane], d = cs[3][lane];
        float4 tot = {a.x + b.x + c.x + d.x, a.y + b.y + c.y + d.y,
                      a.z + b.z + c.z + d.z, a.w + b.w + c.w + d.w};
        *(float4*)&part[(size_t)blockIdx.x * DIM + lane * 4] = tot;
        if (lane == 0) parts1[blockIdx.x] = s1s[0] + s1s[1] + s1s[2] + s1s[3];
    }
    if (blockIdx.x == 0 && threadIdx.x == 0) *accum = 0.0;
}

// --- Phase 1: bandwidth -> exp2 scale factor (pipelined reductions) ---
__global__ __launch_bounds__(256) void k_scale(const double* __restrict__ parts1,
                                               const float* __restrict__ part,
                                               float* __restrict__ scale) {
    __shared__ double sh[256];
    int t = threadIdx.x;
    sh[t] = parts1[t];
    __syncthreads();
    for (int off = 128; off; off >>= 1) {
        if (t < off) sh[t] += sh[t + off];
        __syncthreads();
    }
    double S1 = sh[0];
    __syncthreads();
    float c0 = 0.f, c1 = 0.f, c2 = 0.f, c3 = 0.f;
    #pragma unroll 16
    for (int b = 0; b < CONVB; b += 4) {
        c0 += part[(b + 0) * DIM + t];
        c1 += part[(b + 1) * DIM + t];
        c2 += part[(b + 2) * DIM + t];
        c3 += part[(b + 3) * DIM + t];
    }
    double c = (double)((c0 + c1) + (c2 + c3));
    sh[t] = c * c;
    __syncthreads();
    for (int off = 128; off; off >>= 1) {
        if (t < off) sh[t] += sh[t + off];
        __syncthreads();
    }
    if (t == 0) {
        double S2    = sh[0];
        double n     = (double)NROWS;
        double sumL2 = 2.0 * n * S1 - 2.0 * S2;
        double bw    = sumL2 / (n * n - n) / 4.0;   // / KERNEL_MUL^(KERNEL_NUM//2)
        // u = exp(-L2/(16*bw)) = exp2(scale * L2)
        *scale = (float)(-1.0 / (16.0 * bw * 0.69314718055994530942));
    }
}

// --- Phase 2: barrier-free single-pass bf16 MFMA pair kernel, 256x128 tile ---
__global__ __launch_bounds__(256, 2) void k_pairs(const unsigned short* __restrict__ hi,
                                                  const float* __restrict__ sq,
                                                  const float* __restrict__ scale_p,
                                                  double* __restrict__ accum) {
    // I-major decode: row-group I (panels 2I,2I+1), J = 2I..63.
    int id = blockIdx.x;
    int I = 0;
    for (;;) {
        int cnt = 64 - 2 * I;
        if (id < cnt) break;
        id -= cnt; ++I;
    }
    int J = 2 * I + id;

    __shared__ float wsum[4];

    int t    = threadIdx.x;
    int lane = t & 63;
    int w    = t >> 6;
    int lr   = lane & 15, lq = lane >> 4;
    int Pw   = 2 * I + (w >> 1);                    // this wave's 128-row panel
    int hh   = w & 1;                               // 64-row half within panel

    // Per-wave upper-tri weight: exact single cover of all panel pairs.
    float wgt = (J == Pw) ? 1.0f : (J > Pw) ? 2.0f : 0.0f;
    float sgn = ((Pw < 32) == (J < 32)) ? 1.0f : -1.0f;

    size_t aBase = (size_t)Pw * 4096 + lq * 128 + hh * 64 + lr;
    size_t bBase = (size_t)J  * 4096 + lq * 128 + lr;
    const ushort8* pAh = (const ushort8*)hi + aBase;
    const ushort8* pBh = (const ushort8*)hi + bBase;

    f32x4 acc[4][8];
    #pragma unroll
    for (int m = 0; m < 4; ++m)
        #pragma unroll
        for (int n = 0; n < 8; ++n) acc[m][n] = (f32x4){0.f, 0.f, 0.f, 0.f};

    #pragma unroll
    for (int it = 0; it < DIM / 32; ++it) {
        // 12 coalesced loads then 32 MFMAs (~620 SIMD-cyc burst — covers the
        // other resident wave's load latency). Arrays indexed only by
        // immediately-unrolled m/n -> pure registers.
        bf16x8 aH[4], bH[8];
        #pragma unroll
        for (int m = 0; m < 4; ++m)
            aH[m] = __builtin_bit_cast(bf16x8, pAh[it * 512 + m * 16]);
        #pragma unroll
        for (int n = 0; n < 8; ++n)
            bH[n] = __builtin_bit_cast(bf16x8, pBh[it * 512 + n * 16]);
        #pragma unroll
        for (int m = 0; m < 4; ++m)
            #pragma unroll
            for (int n = 0; n < 8; ++n)
                acc[m][n] = __builtin_amdgcn_mfma_f32_16x16x32_bf16(aH[m], bH[n], acc[m][n], 0, 0, 0);
    }

    // ---- epilogue: L2 -> sum of 5 Gaussian kernels -> reduce
    float scale = *scale_p;
    int ro_eff = Pw * 128 + hh * 64;                // global row base of this wave
    int co_eff = J * 128;
    float4 sqa4[4];
    float  sqbv[8];
    #pragma unroll
    for (int m = 0; m < 4; ++m) sqa4[m] = *(const float4*)&sq[ro_eff + m * 16 + lq * 4];
    #pragma unroll
    for (int n = 0; n < 8; ++n) sqbv[n] = sq[co_eff + n * 16 + lr];

    float tsum = 0.0f;
    #pragma unroll
    for (int m = 0; m < 4; ++m) {
        float sa[4] = {sqa4[m].x, sqa4[m].y, sqa4[m].z, sqa4[m].w};
        #pragma unroll
        for (int n = 0; n < 8; ++n) {
            #pragma unroll
            for (int r = 0; r < 4; ++r) {
                float L2  = sa[r] + sqbv[n] - 2.0f * acc[m][n][r];
                float u   = __builtin_amdgcn_exp2f(scale * L2);
                float u2  = u * u;
                float u4  = u2 * u2;
                float u8  = u4 * u4;
                float u16 = u8 * u8;
                tsum += u + u2 + u4 + u8 + u16;     // 5 kernel scales
            }
        }
    }

    #pragma unroll
    for (int off = 32; off; off >>= 1) tsum += __shfl_xor(tsum, off, 64);
    if (lane == 0) wsum[w] = tsum * sgn * wgt;      // per-wave sign & weight
    __syncthreads();
    if (t == 0) {
        float tot = wsum[0] + wsum[1] + wsum[2] + wsum[3];
        atomicAdd(accum, (double)tot);
    }
}

// --- Finalize: mean normalization ---
__global__ void k_fin(const double* __restrict__ accum, float* __restrict__ out) {
    out[0] = (float)(*accum / ((double)HALF * (double)HALF));
}

extern "C" void kernel_launch(void* const* d_in, const int* in_sizes, int n_in,
                              void* d_out, int out_size, void* d_ws, size_t ws_size,
                              hipStream_t stream) {
    const float* src = (const float*)d_in[0];
    const float* tgt = (const float*)d_in[1];
    float* out = (float*)d_out;

    char* ws = (char*)d_ws;
    double* accum  = (double*)ws;                                // 8 B
    float*  scale  = (float*)(ws + 16);                          // 4 B
    float*  sq     = (float*)(ws + 64);                          // 32768 B
    float*  part   = (float*)(ws + 64 + 32768);                  // 256*256*4 B
    double* parts1 = (double*)(ws + 64 + 32768 + 262144);        // 256*8 B
    unsigned short* hi = (unsigned short*)(ws + 297024);         // 4 MB, 16B-aligned

    k_conv <<<CONVB, 256, 0, stream>>>(src, tgt, hi, sq, part, parts1, accum);
    k_scale<<<1, 256, 0, stream>>>(parts1, part, scale);
    k_pairs<<<NTILE, 256, 0, stream>>>(hi, sq, scale, accum);
    k_fin  <<<1, 1, 0, stream>>>(accum, out);
}

// Round 16
// 109.124 us; speedup vs baseline: 1.2342x; 1.0162x over previous
//
#include <hip/hip_runtime.h>

// MMD loss, N=4096 per side, D=256, fp32.
// R16: k_pairs FROZEN at R15's best (43.6 us; 8 structural variants all
//      plateau 44-48 us -> HIP-level latency plateau, MFMA busy ~6.5 us).
//      Residue attack (was 67 us): k_fin+accum dropped — k_pairs atomicAdds
//      pre-normalized floats into d_out (R13-verified absmax 0.0, jitter
//      ~1e-6 << 2.9e-5); out zeroed by k_conv block 0 (stream-ordered, no
//      fence, no extra dispatch). k_conv: all 8 row-loads hoisted into v[8]
//      (unroll-indexed regs) -> 8 outstanding HBM loads (was latency-bound).
//      Lessons enforced: NO __threadfence (R8-R10 L2 flush), frag/acc arrays
//      indexed only by immediately-unrolled vars (R8/R9 SROA), single-pass
//      bf16 (R10+ absmax 0.0), tiled plane (R6), supertile/I-major order.

#define NROWS 8192
#define HALF  4096
#define DIM   256
#define CONVB 256         // k_conv blocks; 32 rows each (quarter panel)
#define NTILE 1056        // 256x128 tiles: sum_{I=0..31}(64-2I)

typedef __bf16 bf16x8 __attribute__((ext_vector_type(8)));
typedef float f32x4 __attribute__((ext_vector_type(4)));
typedef unsigned short ushort8 __attribute__((ext_vector_type(8)));

__device__ __forceinline__ const float* row_ptr(const float* src, const float* tgt, int r) {
    return (r < HALF) ? (src + (size_t)r * DIM) : (tgt + (size_t)(r - HALF) * DIM);
}

__device__ __forceinline__ unsigned short bf16_rne(float x) {
    unsigned int u = __builtin_bit_cast(unsigned int, x);
    return (unsigned short)((u + 0x7FFFu + ((u >> 16) & 1u)) >> 16);
}

// --- Phase 0: fp32 -> bf16 plane (tiled) + sq[] + colsum/S1 partials ---
// Tiled plane layout: 16B-granule index of (global row R, k-granule g) =
//   (R>>7)*4096 + g*128 + (R&127)        [panel-major, granule-major inside]
__global__ __launch_bounds__(256) void k_conv(const float* __restrict__ src,
                                              const float* __restrict__ tgt,
                                              unsigned short* __restrict__ hi,
                                              float* __restrict__ sq,
                                              float* __restrict__ part,
                                              double* __restrict__ parts1,
                                              float* __restrict__ out) {
    __shared__ __align__(16) unsigned short sh_hi[32 * 32 * 8];  // 16 KB
    __shared__ float4 cs[4][64];
    __shared__ double s1s[4];

    int w = threadIdx.x >> 6, lane = threadIdx.x & 63;
    int r0 = blockIdx.x * 32;                       // 32 rows per block
    int g  = lane >> 1, j = lane & 1;               // lane's float4 = half-granule

    // All 8 row-loads issued up front: 8 outstanding HBM loads per thread.
    float4 v[8];
    #pragma unroll
    for (int i = 0; i < 8; ++i) {
        int row = r0 + w * 8 + i;
        v[i] = ((const float4*)row_ptr(src, tgt, row))[lane];   // coalesced
    }

    float4 csum = {0.f, 0.f, 0.f, 0.f};
    double s1w = 0.0;
    #pragma unroll
    for (int i = 0; i < 8; ++i) {
        int rl  = w * 8 + i;                        // local row 0..31
        float xs[4] = {v[i].x, v[i].y, v[i].z, v[i].w};
        unsigned short hs[4];
        #pragma unroll
        for (int k = 0; k < 4; ++k) hs[k] = bf16_rne(xs[k]);
        ushort4 h4 = {hs[0], hs[1], hs[2], hs[3]};
        int so = (g * 32 + rl) * 8 + j * 4;
        *(ushort4*)&sh_hi[so] = h4;
        csum.x += xs[0]; csum.y += xs[1]; csum.z += xs[2]; csum.w += xs[3];
        float s = xs[0] * xs[0] + xs[1] * xs[1] + xs[2] * xs[2] + xs[3] * xs[3];
        #pragma unroll
        for (int off = 32; off; off >>= 1) s += __shfl_xor(s, off, 64);
        if (lane == 0) { sq[r0 + rl] = s; s1w += (double)s; }
    }
    __syncthreads();
    // Coalesced tiled write-out: 1024 chunks of 16 B.
    int panel = blockIdx.x >> 2, quarter = blockIdx.x & 3;
    #pragma unroll
    for (int c = threadIdx.x; c < 1024; c += 256) {
        int gg = c >> 5, r = c & 31;
        size_t goff = (((size_t)panel * 32 + gg) * 128 + quarter * 32 + r) * 8;
        *(ushort8*)&hi[goff] = *(const ushort8*)&sh_hi[c * 8];
    }
    // colsum + S1 partials (per-block slots, no contention)
    cs[w][lane] = csum;
    if (lane == 0) s1s[w] = s1w;
    __syncthreads();
    if (w == 0) {
        float4 a = cs[0][lane], b = cs[1][lane], c = cs[2][lane], d = cs[3][lane];
        float4 tot = {a.x + b.x + c.x + d.x, a.y + b.y + c.y + d.y,
                      a.z + b.z + c.z + d.z, a.w + b.w + c.w + d.w};
        *(float4*)&part[(size_t)blockIdx.x * DIM + lane * 4] = tot;
        if (lane == 0) parts1[blockIdx.x] = s1s[0] + s1s[1] + s1s[2] + s1s[3];
    }
    if (blockIdx.x == 0 && threadIdx.x == 0) out[0] = 0.0f;  // d_out was 0xAA
}

// --- Phase 1: bandwidth -> exp2 scale factor (pipelined reductions) ---
__global__ __launch_bounds__(256) void k_scale(const double* __restrict__ parts1,
                                               const float* __restrict__ part,
                                               float* __restrict__ scale) {
    __shared__ double sh[256];
    int t = threadIdx.x;
    sh[t] = parts1[t];
    __syncthreads();
    for (int off = 128; off; off >>= 1) {
        if (t < off) sh[t] += sh[t + off];
        __syncthreads();
    }
    double S1 = sh[0];
    __syncthreads();
    float c0 = 0.f, c1 = 0.f, c2 = 0.f, c3 = 0.f;
    #pragma unroll 16
    for (int b = 0; b < CONVB; b += 4) {
        c0 += part[(b + 0) * DIM + t];
        c1 += part[(b + 1) * DIM + t];
        c2 += part[(b + 2) * DIM + t];
        c3 += part[(b + 3) * DIM + t];
    }
    double c = (double)((c0 + c1) + (c2 + c3));
    sh[t] = c * c;
    __syncthreads();
    for (int off = 128; off; off >>= 1) {
        if (t < off) sh[t] += sh[t + off];
        __syncthreads();
    }
    if (t == 0) {
        double S2    = sh[0];
        double n     = (double)NROWS;
        double sumL2 = 2.0 * n * S1 - 2.0 * S2;
        double bw    = sumL2 / (n * n - n) / 4.0;   // / KERNEL_MUL^(KERNEL_NUM//2)
        // u = exp(-L2/(16*bw)) = exp2(scale * L2)
        *scale = (float)(-1.0 / (16.0 * bw * 0.69314718055994530942));
    }
}

// --- Phase 2: barrier-free single-pass bf16 MFMA pair kernel, 256x128 tile ---
__global__ __launch_bounds__(256, 2) void k_pairs(const unsigned short* __restrict__ hi,
                                                  const float* __restrict__ sq,
                                                  const float* __restrict__ scale_p,
                                                  float* __restrict__ out) {
    // I-major decode: row-group I (panels 2I,2I+1), J = 2I..63.
    int id = blockIdx.x;
    int I = 0;
    for (;;) {
        int cnt = 64 - 2 * I;
        if (id < cnt) break;
        id -= cnt; ++I;
    }
    int J = 2 * I + id;

    __shared__ float wsum[4];

    int t    = threadIdx.x;
    int lane = t & 63;
    int w    = t >> 6;
    int lr   = lane & 15, lq = lane >> 4;
    int Pw   = 2 * I + (w >> 1);                    // this wave's 128-row panel
    int hh   = w & 1;                               // 64-row half within panel

    // Per-wave upper-tri weight: exact single cover of all panel pairs.
    float wgt = (J == Pw) ? 1.0f : (J > Pw) ? 2.0f : 0.0f;
    float sgn = ((Pw < 32) == (J < 32)) ? 1.0f : -1.0f;

    size_t aBase = (size_t)Pw * 4096 + lq * 128 + hh * 64 + lr;
    size_t bBase = (size_t)J  * 4096 + lq * 128 + lr;
    const ushort8* pAh = (const ushort8*)hi + aBase;
    const ushort8* pBh = (const ushort8*)hi + bBase;

    f32x4 acc[4][8];
    #pragma unroll
    for (int m = 0; m < 4; ++m)
        #pragma unroll
        for (int n = 0; n < 8; ++n) acc[m][n] = (f32x4){0.f, 0.f, 0.f, 0.f};

    #pragma unroll
    for (int it = 0; it < DIM / 32; ++it) {
        // 12 coalesced loads then 32 MFMAs (~620 SIMD-cyc burst). Arrays
        // indexed only by immediately-unrolled m/n -> pure registers.
        bf16x8 aH[4], bH[8];
        #pragma unroll
        for (int m = 0; m < 4; ++m)
            aH[m] = __builtin_bit_cast(bf16x8, pAh[it * 512 + m * 16]);
        #pragma unroll
        for (int n = 0; n < 8; ++n)
            bH[n] = __builtin_bit_cast(bf16x8, pBh[it * 512 + n * 16]);
        #pragma unroll
        for (int m = 0; m < 4; ++m)
            #pragma unroll
            for (int n = 0; n < 8; ++n)
                acc[m][n] = __builtin_amdgcn_mfma_f32_16x16x32_bf16(aH[m], bH[n], acc[m][n], 0, 0, 0);
    }

    // ---- epilogue: L2 -> sum of 5 Gaussian kernels -> reduce
    float scale = *scale_p;
    int ro_eff = Pw * 128 + hh * 64;                // global row base of this wave
    int co_eff = J * 128;
    float4 sqa4[4];
    float  sqbv[8];
    #pragma unroll
    for (int m = 0; m < 4; ++m) sqa4[m] = *(const float4*)&sq[ro_eff + m * 16 + lq * 4];
    #pragma unroll
    for (int n = 0; n < 8; ++n) sqbv[n] = sq[co_eff + n * 16 + lr];

    float tsum = 0.0f;
    #pragma unroll
    for (int m = 0; m < 4; ++m) {
        float sa[4] = {sqa4[m].x, sqa4[m].y, sqa4[m].z, sqa4[m].w};
        #pragma unroll
        for (int n = 0; n < 8; ++n) {
            #pragma unroll
            for (int r = 0; r < 4; ++r) {
                float L2  = sa[r] + sqbv[n] - 2.0f * acc[m][n][r];
                float u   = __builtin_amdgcn_exp2f(scale * L2);
                float u2  = u * u;
                float u4  = u2 * u2;
                float u8  = u4 * u4;
                float u16 = u8 * u8;
                tsum += u + u2 + u4 + u8 + u16;     // 5 kernel scales
            }
        }
    }

    #pragma unroll
    for (int off = 32; off; off >>= 1) tsum += __shfl_xor(tsum, off, 64);
    if (lane == 0) wsum[w] = tsum * sgn * wgt;      // per-wave sign & weight
    __syncthreads();
    if (t == 0) {
        float tot = wsum[0] + wsum[1] + wsum[2] + wsum[3];
        // pre-normalized float atomic straight into d_out (R13-verified)
        atomicAdd(out, tot * (1.0f / ((float)HALF * (float)HALF)));
    }
}

extern "C" void kernel_launch(void* const* d_in, const int* in_sizes, int n_in,
                              void* d_out, int out_size, void* d_ws, size_t ws_size,
                              hipStream_t stream) {
    const float* src = (const float*)d_in[0];
    const float* tgt = (const float*)d_in[1];
    float* out = (float*)d_out;

    char* ws = (char*)d_ws;
    float*  scale  = (float*)(ws + 16);                          // 4 B
    float*  sq     = (float*)(ws + 64);                          // 32768 B
    float*  part   = (float*)(ws + 64 + 32768);                  // 256*256*4 B
    double* parts1 = (double*)(ws + 64 + 32768 + 262144);        // 256*8 B
    unsigned short* hi = (unsigned short*)(ws + 297024);         // 4 MB, 16B-aligned

    k_conv <<<CONVB, 256, 0, stream>>>(src, tgt, hi, sq, part, parts1, out);
    k_scale<<<1, 256, 0, stream>>>(parts1, part, scale);
    k_pairs<<<NTILE, 256, 0, stream>>>(hi, sq, scale, out);
}